// Round 4
// baseline (422.023 us; speedup 1.0000x reference)
//
#include <hip/hip_runtime.h>

typedef float v2f __attribute__((ext_vector_type(2)));
typedef float v4f __attribute__((ext_vector_type(4)));

#define TT 512
#define NB 512
#define II 32
#define HH 64

static __device__ __forceinline__ float fexp2f(float x){ return __builtin_amdgcn_exp2f(x); }
static __device__ __forceinline__ float frcpf(float x){ return __builtin_amdgcn_rcpf(x); }
static __device__ __forceinline__ float sigf(float x){ return frcpf(1.0f + fexp2f(-1.442695040888963f*x)); }
static __device__ __forceinline__ float tanhf_fast(float x){ return 1.0f - 2.0f*frcpf(1.0f + fexp2f(2.885390081777926f*x)); }

static __device__ __forceinline__ v2f pfma(v2f a, v2f b, v2f c){ return __builtin_elementwise_fma(a, b, c); }
static __device__ __forceinline__ v2f lo2(v4f v){ return __builtin_shufflevector(v, v, 0, 1); } // subreg alias, 0 insts
static __device__ __forceinline__ v2f hi2(v4f v){ return __builtin_shufflevector(v, v, 2, 3); }

// load 8 consecutive floats (16B-aligned) as two v4f, split to 4 v2f halves (free)
static __device__ __forceinline__ void ld8v(const float* p, v2f* d){
  v4f a = ((const v4f*)p)[0], b = ((const v4f*)p)[1];
  d[0] = lo2(a); d[1] = hi2(a); d[2] = lo2(b); d[3] = hi2(b);
}

// butterfly sum across the 4 lanes of a quad (ks dimension) via DPP quad_perm
static __device__ __forceinline__ float quad_sum(float x){
  int xi = __builtin_bit_cast(int, x);
  int y  = __builtin_amdgcn_update_dpp(xi, xi, 0xB1, 0xF, 0xF, false); // quad_perm [1,0,3,2]
  x += __builtin_bit_cast(float, y);
  xi = __builtin_bit_cast(int, x);
  y  = __builtin_amdgcn_update_dpp(xi, xi, 0x4E, 0xF, 0xF, false);     // quad_perm [2,3,0,1]
  x += __builtin_bit_cast(float, y);
  return x;
}

// 256 threads = 1 batch = 4 waves; grid 512 -> 2 blocks/CU.
// waves_per_eu(2,2) -> 256-VGPR budget. v4f loads + shufflevector halves keep
// true pressure ~247 <= 256 so weights stay in arch VGPRs (R3: demand ~280
// overflowed into AGPRs -> per-phase accvgpr copies).
__global__ __attribute__((amdgpu_flat_work_group_size(256,256)))
__attribute__((amdgpu_waves_per_eu(2,2)))
void gru2_fused(
    const float* __restrict__ x,
    const float* __restrict__ Wih0, const float* __restrict__ Whh0,
    const float* __restrict__ bih0, const float* __restrict__ bhh0,
    const float* __restrict__ Wih1, const float* __restrict__ Whh1,
    const float* __restrict__ b_ih1, const float* __restrict__ b_hh1,
    const float* __restrict__ fcw, const float* __restrict__ fcb,
    float* __restrict__ out)
{
  const int tid = threadIdx.x;
  const int j   = tid >> 2;   // 0..63 hidden unit owned
  const int ks  = tid & 3;    // 0..3 k-slice
  const int b   = blockIdx.x;

  __shared__ float h0buf[2][64]; // pingpong
  __shared__ float h1buf[2][64];

  // ---- persistent per-thread weights (k-slice ks of gate rows j, 64+j, 128+j) ----
  v2f wih0[3][4], whh0[3][8], wih1[3][8], whh1[3][8];
#pragma unroll
  for (int g = 0; g < 3; ++g) {
    const int row = g*64 + j;
    ld8v(Wih0 + row*II + ks*8,      wih0[g]);
    ld8v(Whh0 + row*HH + ks*16,     whh0[g]);
    ld8v(Whh0 + row*HH + ks*16 + 8, whh0[g] + 4);
    ld8v(Wih1 + row*HH + ks*16,     wih1[g]);
    ld8v(Wih1 + row*HH + ks*16 + 8, wih1[g] + 4);
    ld8v(Whh1 + row*HH + ks*16,     whh1[g]);
    ld8v(Whh1 + row*HH + ks*16 + 8, whh1[g] + 4);
  }
  // pin: value no longer a pure load result -> cannot be rematerialized.
#pragma unroll
  for (int g = 0; g < 3; ++g) {
#pragma unroll
    for (int i = 0; i < 4; ++i) asm volatile("" : "+v"(wih0[g][i]));
#pragma unroll
    for (int i = 0; i < 8; ++i) {
      asm volatile("" : "+v"(whh0[g][i]));
      asm volatile("" : "+v"(wih1[g][i]));
      asm volatile("" : "+v"(whh1[g][i]));
    }
  }

  const float br0  = bih0[j]      + bhh0[j];
  const float bz0  = bih0[64+j]   + bhh0[64+j];
  const float bin0 = bih0[128+j];
  const float bhn0 = bhh0[128+j];
  const float br1  = b_ih1[j]     + b_hh1[j];
  const float bz1  = b_ih1[64+j]  + b_hh1[64+j];
  const float bin1 = b_ih1[128+j];
  const float bhn1 = b_hh1[128+j];

  const float* xb = x + (size_t)b * (TT*II);

  // xc = x[0]
  v2f xc[4];
  ld8v(xb + ks*8, xc);

  // h1[-1] = 0
  if (tid < 64) h1buf[0][tid] = 0.0f;

  // ---- prologue: layer0 step t=0 with h_prev = 0 ----
  float hp0, hp1 = 0.0f;
  {
    v2f ar = {0.f,0.f}, az = {0.f,0.f}, an = {0.f,0.f};
#pragma unroll
    for (int i = 0; i < 4; ++i) {
      ar = pfma(wih0[0][i], xc[i], ar);
      az = pfma(wih0[1][i], xc[i], az);
      an = pfma(wih0[2][i], xc[i], an);
    }
    const float pr  = quad_sum(ar.x + ar.y);
    const float pz  = quad_sum(az.x + az.y);
    const float pni = quad_sum(an.x + an.y);
    const float r = sigf(pr + br0);
    const float z = sigf(pz + bz0);
    const float n = tanhf_fast(pni + bin0 + r*bhn0);
    hp0 = n - z*n;                  // h0out[0]
    if (ks == 0) h0buf[0][j] = hp0;
  }
  // xc = x[1]
  ld8v(xb + II + ks*8, xc);
  __syncthreads();

  // ---- main: phase p computes layer0 step p+1 AND layer1 step p ----
  for (int p = 0; p < TT-1; ++p) {
    const int cur = p & 1, nxt = cur ^ 1;

    // hs = h0out[p] slice (shared: layer0 h_prev AND layer1 input)
    // bs = h1[p-1] slice
    v2f hs[8], bs[8];
    ld8v(&h0buf[cur][ks*16],     hs);
    ld8v(&h0buf[cur][ks*16 + 8], hs + 4);
    ld8v(&h1buf[cur][ks*16],     bs);
    ld8v(&h1buf[cur][ks*16 + 8], bs + 4);

    v2f ar0 = {0.f,0.f}, az0 = {0.f,0.f}, ani0 = {0.f,0.f}, anh0 = {0.f,0.f};
    v2f ar1 = {0.f,0.f}, az1 = {0.f,0.f}, ani1 = {0.f,0.f}, anh1 = {0.f,0.f};
#pragma unroll
    for (int i = 0; i < 4; ++i) {
      ar0  = pfma(wih0[0][i], xc[i], ar0);
      az0  = pfma(wih0[1][i], xc[i], az0);
      ani0 = pfma(wih0[2][i], xc[i], ani0);
    }
    // reload xc in place for next phase (x[p+2]); latency covered by the
    // rest of this phase.
    {
      const int tn = (p+2 < TT) ? (p+2) : (TT-1);
      ld8v(xb + tn*II + ks*8, xc);
    }
#pragma unroll
    for (int k = 0; k < 8; ++k) {
      ar0  = pfma(whh0[0][k], hs[k], ar0);
      az0  = pfma(whh0[1][k], hs[k], az0);
      anh0 = pfma(whh0[2][k], hs[k], anh0);
      ar1  = pfma(wih1[0][k], hs[k], ar1);
      az1  = pfma(wih1[1][k], hs[k], az1);
      ani1 = pfma(wih1[2][k], hs[k], ani1);
      ar1  = pfma(whh1[0][k], bs[k], ar1);
      az1  = pfma(whh1[1][k], bs[k], az1);
      anh1 = pfma(whh1[2][k], bs[k], anh1);
    }
    const float pr0  = quad_sum(ar0.x  + ar0.y);
    const float pz0  = quad_sum(az0.x  + az0.y);
    const float pni0 = quad_sum(ani0.x + ani0.y);
    const float pnh0 = quad_sum(anh0.x + anh0.y);
    const float pr1  = quad_sum(ar1.x  + ar1.y);
    const float pz1  = quad_sum(az1.x  + az1.y);
    const float pni1 = quad_sum(ani1.x + ani1.y);
    const float pnh1 = quad_sum(anh1.x + anh1.y);

    // layer0 step p+1
    {
      const float r = sigf(pr0 + br0);
      const float z = sigf(pz0 + bz0);
      const float n = tanhf_fast(pni0 + bin0 + r*(pnh0 + bhn0));
      hp0 = n + z*(hp0 - n);
      if (ks == 0) h0buf[nxt][j] = hp0;
    }
    // layer1 step p
    {
      const float r = sigf(pr1 + br1);
      const float z = sigf(pz1 + bz1);
      const float n = tanhf_fast(pni1 + bin1 + r*(pnh1 + bhn1));
      hp1 = n + z*(hp1 - n);
      if (ks == 1) h1buf[nxt][j] = hp1;
    }
    __syncthreads();
  }

  // ---- epilogue phase p=511: layer1 only ----
  {
    const int cur = (TT-1) & 1; // = 1
    v2f hs[8], bs[8];
    ld8v(&h0buf[cur][ks*16],     hs);
    ld8v(&h0buf[cur][ks*16 + 8], hs + 4);
    ld8v(&h1buf[cur][ks*16],     bs);
    ld8v(&h1buf[cur][ks*16 + 8], bs + 4);
    v2f ar1 = {0.f,0.f}, az1 = {0.f,0.f}, ani1 = {0.f,0.f}, anh1 = {0.f,0.f};
#pragma unroll
    for (int k = 0; k < 8; ++k) {
      ar1  = pfma(wih1[0][k], hs[k], ar1);
      az1  = pfma(wih1[1][k], hs[k], az1);
      ani1 = pfma(wih1[2][k], hs[k], ani1);
      ar1  = pfma(whh1[0][k], bs[k], ar1);
      az1  = pfma(whh1[1][k], bs[k], az1);
      anh1 = pfma(whh1[2][k], bs[k], anh1);
    }
    const float pr1  = quad_sum(ar1.x  + ar1.y);
    const float pz1  = quad_sum(az1.x  + az1.y);
    const float pni1 = quad_sum(ani1.x + ani1.y);
    const float pnh1 = quad_sum(anh1.x + anh1.y);
    const float r = sigf(pr1 + br1);
    const float z = sigf(pz1 + bz1);
    const float n = tanhf_fast(pni1 + bin1 + r*(pnh1 + bhn1));
    hp1 = n + z*(hp1 - n);          // h1[511]
  }

  // ---- FC epilogue: out[b] = fcb + sum_j h1[511][j]*fcw[j] ----
  __syncthreads();                   // safe to reuse h1buf[0]
  if (ks == 0) h1buf[0][j] = hp1;
  __syncthreads();
  if (tid < 64) {
    float v = h1buf[0][tid] * fcw[tid];
#pragma unroll
    for (int off = 32; off >= 1; off >>= 1)
      v += __shfl_xor(v, off, 64);
    if (tid == 0) out[b] = v + fcb[0];
  }
}

extern "C" void kernel_launch(void* const* d_in, const int* in_sizes, int n_in,
                              void* d_out, int out_size, void* d_ws, size_t ws_size,
                              hipStream_t stream) {
  const float* x    = (const float*)d_in[0];
  const float* Wih0 = (const float*)d_in[1];
  const float* Whh0 = (const float*)d_in[2];
  const float* bih0 = (const float*)d_in[3];
  const float* bhh0 = (const float*)d_in[4];
  const float* Wih1 = (const float*)d_in[5];
  const float* Whh1 = (const float*)d_in[6];
  const float* bih1 = (const float*)d_in[7];
  const float* bhh1 = (const float*)d_in[8];
  const float* fcw  = (const float*)d_in[9];
  const float* fcb  = (const float*)d_in[10];
  float* out = (float*)d_out;

  gru2_fused<<<dim3(NB), dim3(256), 0, stream>>>(
      x, Wih0, Whh0, bih0, bhh0, Wih1, Whh1, bih1, bhh1, fcw, fcb, out);
}

// Round 6
// 415.617 us; speedup vs baseline: 1.0154x; 1.0154x over previous
//
#include <hip/hip_runtime.h>

typedef _Float16 h2 __attribute__((ext_vector_type(2)));
typedef _Float16 h8 __attribute__((ext_vector_type(8)));

#define TT 512
#define NB 512
#define II 32
#define HH 64

static __device__ __forceinline__ float fexp2f(float x){ return __builtin_amdgcn_exp2f(x); }
static __device__ __forceinline__ float frcpf(float x){ return __builtin_amdgcn_rcpf(x); }
static __device__ __forceinline__ float sigf(float x){ return frcpf(1.0f + fexp2f(-1.442695040888963f*x)); }
static __device__ __forceinline__ float tanhf_fast(float x){ return 1.0f - 2.0f*frcpf(1.0f + fexp2f(2.885390081777926f*x)); }

// v_dot2_f32_f16: 2 f16 MACs, f32 accumulate, single full-rate VALU inst
static __device__ __forceinline__ float fdot2(h2 a, h2 b, float c){
  return __builtin_amdgcn_fdot2(a, b, c, false);
}

// butterfly sum across the 4 lanes of a quad (ks dimension) via DPP quad_perm
static __device__ __forceinline__ float quad_sum(float x){
  int xi = __builtin_bit_cast(int, x);
  int y  = __builtin_amdgcn_update_dpp(xi, xi, 0xB1, 0xF, 0xF, false); // quad_perm [1,0,3,2]
  x += __builtin_bit_cast(float, y);
  xi = __builtin_bit_cast(int, x);
  y  = __builtin_amdgcn_update_dpp(xi, xi, 0x4E, 0xF, 0xF, false);     // quad_perm [2,3,0,1]
  x += __builtin_bit_cast(float, y);
  return x;
}

// v_cvt_pkrtz_f16_f32 returns __fp16 vector; bit_cast to our h2 (same layout)
static __device__ __forceinline__ h2 pkrtz(float a, float b){
  return __builtin_bit_cast(h2, __builtin_amdgcn_cvt_pkrtz(a, b));
}

// convert 2 consecutive f32 weights to one packed h2 (RTE via scalar casts)
static __device__ __forceinline__ h2 cvtw(const float* p){
  h2 r; r.x = (_Float16)p[0]; r.y = (_Float16)p[1]; return r;
}

// load 8 f32, convert to 4 packed h2 via v_cvt_pkrtz_f16_f32
static __device__ __forceinline__ void ldx8(const float* p, h2* d){
  float4 a = ((const float4*)p)[0], b = ((const float4*)p)[1];
  d[0] = pkrtz(a.x, a.y);
  d[1] = pkrtz(a.z, a.w);
  d[2] = pkrtz(b.x, b.y);
  d[3] = pkrtz(b.z, b.w);
}

// read 8 h2 (16 f16) from 32B of LDS via two b128 reads; shufflevector = free subreg
static __device__ __forceinline__ void ldh16(const _Float16* p, h2* d){
  h8 a = ((const h8*)p)[0], b = ((const h8*)p)[1];
  d[0] = __builtin_shufflevector(a, a, 0, 1); d[1] = __builtin_shufflevector(a, a, 2, 3);
  d[2] = __builtin_shufflevector(a, a, 4, 5); d[3] = __builtin_shufflevector(a, a, 6, 7);
  d[4] = __builtin_shufflevector(b, b, 0, 1); d[5] = __builtin_shufflevector(b, b, 2, 3);
  d[6] = __builtin_shufflevector(b, b, 4, 5); d[7] = __builtin_shufflevector(b, b, 6, 7);
}

// 256 threads = 1 batch = 4 waves; grid 512 -> 2 blocks/CU.
// f16 weights via v_dot2_f32_f16: 168 weight floats -> 84 VGPRs, total demand
// ~140 fits the arch-VGPR file -> no AGPR split, no per-phase copy bloat
// (R3/R4: f32 weights overflowed 256 -> ~168 accvgpr reads per phase).
// Recurrent carry (hp0/hp1) stays f32 in registers; f16 only perturbs
// per-step gate operands (no compounding through the carry path).
__global__ __attribute__((amdgpu_flat_work_group_size(256,256)))
__attribute__((amdgpu_waves_per_eu(2,2)))
void gru2_fused(
    const float* __restrict__ x,
    const float* __restrict__ Wih0, const float* __restrict__ Whh0,
    const float* __restrict__ bih0, const float* __restrict__ bhh0,
    const float* __restrict__ Wih1, const float* __restrict__ Whh1,
    const float* __restrict__ b_ih1, const float* __restrict__ b_hh1,
    const float* __restrict__ fcw, const float* __restrict__ fcb,
    float* __restrict__ out)
{
  const int tid = threadIdx.x;
  const int j   = tid >> 2;   // 0..63 hidden unit owned
  const int ks  = tid & 3;    // 0..3 k-slice
  const int b   = blockIdx.x;

  __shared__ _Float16 h0buf[2][64]; // pingpong, f16 (dot operands only)
  __shared__ _Float16 h1buf[2][64];
  __shared__ float    red[64];

  // ---- persistent per-thread weights, packed f16 (RTE) ----
  h2 wih0[3][4], whh0[3][8], wih1[3][8], whh1[3][8];
#pragma unroll
  for (int g = 0; g < 3; ++g) {
    const int row = g*64 + j;
#pragma unroll
    for (int i = 0; i < 4; ++i)
      wih0[g][i] = cvtw(Wih0 + row*II + ks*8 + 2*i);
#pragma unroll
    for (int k = 0; k < 8; ++k) {
      whh0[g][k] = cvtw(Whh0 + row*HH + ks*16 + 2*k);
      wih1[g][k] = cvtw(Wih1 + row*HH + ks*16 + 2*k);
      whh1[g][k] = cvtw(Whh1 + row*HH + ks*16 + 2*k);
    }
  }
  // pin each packed weight (1 VGPR each) so the allocator cannot
  // rematerialize the load+cvt chain inside the loop.
#pragma unroll
  for (int g = 0; g < 3; ++g) {
#pragma unroll
    for (int i = 0; i < 4; ++i) asm volatile("" : "+v"(wih0[g][i]));
#pragma unroll
    for (int k = 0; k < 8; ++k) {
      asm volatile("" : "+v"(whh0[g][k]));
      asm volatile("" : "+v"(wih1[g][k]));
      asm volatile("" : "+v"(whh1[g][k]));
    }
  }

  const float br0  = bih0[j]      + bhh0[j];
  const float bz0  = bih0[64+j]   + bhh0[64+j];
  const float bin0 = bih0[128+j];
  const float bhn0 = bhh0[128+j];
  const float br1  = b_ih1[j]     + b_hh1[j];
  const float bz1  = b_ih1[64+j]  + b_hh1[64+j];
  const float bin1 = b_ih1[128+j];
  const float bhn1 = b_hh1[128+j];

  const float* xb = x + (size_t)b * (TT*II);

  // xc = x[0] (packed f16)
  h2 xc[4];
  ldx8(xb + ks*8, xc);

  // h1[-1] = 0
  if (tid < 64) h1buf[0][tid] = (_Float16)0.0f;

  // ---- prologue: layer0 step t=0 with h_prev = 0 ----
  float hp0, hp1 = 0.0f; // recurrent carries, f32, replicated in all ks lanes
  {
    float pr = 0.f, pz = 0.f, pni = 0.f;
#pragma unroll
    for (int i = 0; i < 4; ++i) {
      pr  = fdot2(wih0[0][i], xc[i], pr);
      pz  = fdot2(wih0[1][i], xc[i], pz);
      pni = fdot2(wih0[2][i], xc[i], pni);
    }
    pr = quad_sum(pr); pz = quad_sum(pz); pni = quad_sum(pni);
    const float r = sigf(pr + br0);
    const float z = sigf(pz + bz0);
    const float n = tanhf_fast(pni + bin0 + r*bhn0);
    hp0 = n - z*n;                  // h0out[0]
    if (ks == 0) h0buf[0][j] = (_Float16)hp0;
  }
  // xc = x[1]
  ldx8(xb + II + ks*8, xc);
  __syncthreads();

  // ---- main: phase p computes layer0 step p+1 AND layer1 step p ----
  for (int p = 0; p < TT-1; ++p) {
    const int cur = p & 1, nxt = cur ^ 1;

    // hs = h0out[p] slice (shared: layer0 h_prev AND layer1 input)
    // bs = h1[p-1] slice
    h2 hs[8], bs[8];
    ldh16(&h0buf[cur][ks*16], hs);
    ldh16(&h1buf[cur][ks*16], bs);

    float pr0=0.f, pz0=0.f, pni0=0.f, pnh0=0.f;
    float pr1=0.f, pz1=0.f, pni1=0.f, pnh1=0.f;
#pragma unroll
    for (int i = 0; i < 4; ++i) {
      pr0  = fdot2(wih0[0][i], xc[i], pr0);
      pz0  = fdot2(wih0[1][i], xc[i], pz0);
      pni0 = fdot2(wih0[2][i], xc[i], pni0);
    }
    // reload xc in place for next phase (x[p+2]); rest of phase covers latency
    {
      const int tn = (p+2 < TT) ? (p+2) : (TT-1);
      ldx8(xb + tn*II + ks*8, xc);
    }
#pragma unroll
    for (int k = 0; k < 8; ++k) {
      pr0  = fdot2(whh0[0][k], hs[k], pr0);
      pz0  = fdot2(whh0[1][k], hs[k], pz0);
      pnh0 = fdot2(whh0[2][k], hs[k], pnh0);
      pr1  = fdot2(wih1[0][k], hs[k], pr1);
      pz1  = fdot2(wih1[1][k], hs[k], pz1);
      pni1 = fdot2(wih1[2][k], hs[k], pni1);
      pr1  = fdot2(whh1[0][k], bs[k], pr1);
      pz1  = fdot2(whh1[1][k], bs[k], pz1);
      pnh1 = fdot2(whh1[2][k], bs[k], pnh1);
    }
    pr0 = quad_sum(pr0); pz0 = quad_sum(pz0); pni0 = quad_sum(pni0); pnh0 = quad_sum(pnh0);
    pr1 = quad_sum(pr1); pz1 = quad_sum(pz1); pni1 = quad_sum(pni1); pnh1 = quad_sum(pnh1);

    // layer0 step p+1
    {
      const float r = sigf(pr0 + br0);
      const float z = sigf(pz0 + bz0);
      const float n = tanhf_fast(pni0 + bin0 + r*(pnh0 + bhn0));
      hp0 = n + z*(hp0 - n);
      if (ks == 0) h0buf[nxt][j] = (_Float16)hp0;
    }
    // layer1 step p
    {
      const float r = sigf(pr1 + br1);
      const float z = sigf(pz1 + bz1);
      const float n = tanhf_fast(pni1 + bin1 + r*(pnh1 + bhn1));
      hp1 = n + z*(hp1 - n);
      if (ks == 1) h1buf[nxt][j] = (_Float16)hp1;
    }
    __syncthreads();
  }

  // ---- epilogue phase p=511: layer1 only ----
  {
    const int cur = (TT-1) & 1; // = 1
    h2 hs[8], bs[8];
    ldh16(&h0buf[cur][ks*16], hs);
    ldh16(&h1buf[cur][ks*16], bs);
    float pr1=0.f, pz1=0.f, pni1=0.f, pnh1=0.f;
#pragma unroll
    for (int k = 0; k < 8; ++k) {
      pr1  = fdot2(wih1[0][k], hs[k], pr1);
      pz1  = fdot2(wih1[1][k], hs[k], pz1);
      pni1 = fdot2(wih1[2][k], hs[k], pni1);
      pr1  = fdot2(whh1[0][k], bs[k], pr1);
      pz1  = fdot2(whh1[1][k], bs[k], pz1);
      pnh1 = fdot2(whh1[2][k], bs[k], pnh1);
    }
    pr1 = quad_sum(pr1); pz1 = quad_sum(pz1); pni1 = quad_sum(pni1); pnh1 = quad_sum(pnh1);
    const float r = sigf(pr1 + br1);
    const float z = sigf(pz1 + bz1);
    const float n = tanhf_fast(pni1 + bin1 + r*(pnh1 + bhn1));
    hp1 = n + z*(hp1 - n);          // h1[511], f32
  }

  // ---- FC epilogue: out[b] = fcb + sum_j h1[511][j]*fcw[j] (f32 path) ----
  __syncthreads();
  if (ks == 0) red[j] = hp1;
  __syncthreads();
  if (tid < 64) {
    float v = red[tid] * fcw[tid];
#pragma unroll
    for (int off = 32; off >= 1; off >>= 1)
      v += __shfl_xor(v, off, 64);
    if (tid == 0) out[b] = v + fcb[0];
  }
}

extern "C" void kernel_launch(void* const* d_in, const int* in_sizes, int n_in,
                              void* d_out, int out_size, void* d_ws, size_t ws_size,
                              hipStream_t stream) {
  const float* x    = (const float*)d_in[0];
  const float* Wih0 = (const float*)d_in[1];
  const float* Whh0 = (const float*)d_in[2];
  const float* bih0 = (const float*)d_in[3];
  const float* bhh0 = (const float*)d_in[4];
  const float* Wih1 = (const float*)d_in[5];
  const float* Whh1 = (const float*)d_in[6];
  const float* bih1 = (const float*)d_in[7];
  const float* bhh1 = (const float*)d_in[8];
  const float* fcw  = (const float*)d_in[9];
  const float* fcb  = (const float*)d_in[10];
  float* out = (float*)d_out;

  gru2_fused<<<dim3(NB), dim3(256), 0, stream>>>(
      x, Wih0, Whh0, bih0, bhh0, Wih1, Whh1, bih1, bhh1, fcw, fcb, out);
}